// Round 1
// 532.271 us; speedup vs baseline: 1.4099x; 1.4099x over previous
//
#include <hip/hip_runtime.h>
#include <hip/hip_fp16.h>
#include <stdint.h>

#define IN_F   4096
#define OUT_F  4096
#define M_ROWS 8192

typedef _Float16 v8h __attribute__((ext_vector_type(8)));
typedef float    v4f __attribute__((ext_vector_type(4)));

// ================== Kernel 1: fused prep ==================
// blocks 0..2047: dequant 3-bit -> f16 w;  blocks 2048..18431: cast x f32 -> f16.
// Both memory-bound; fusing lets them overlap instead of serializing.
__global__ void __launch_bounds__(256)
prep_kernel(const int* __restrict__ q, const float* __restrict__ norm,
            _Float16* __restrict__ w, const float* __restrict__ x,
            _Float16* __restrict__ xo) {
    int blk = blockIdx.x;
    if (blk < 2048) {
        int g = blk * 256 + threadIdx.x;   // 524288 groups
        const int4* p = (const int4*)(q + (size_t)g * 12);
        int4 q0 = p[0], q1 = p[1], q2 = p[2];
        uint32_t b[12] = {(uint32_t)q0.x, (uint32_t)q0.y, (uint32_t)q0.z, (uint32_t)q0.w,
                          (uint32_t)q1.x, (uint32_t)q1.y, (uint32_t)q1.z, (uint32_t)q1.w,
                          (uint32_t)q2.x, (uint32_t)q2.y, (uint32_t)q2.z, (uint32_t)q2.w};
        uint64_t lo = 0, hi = 0;
#pragma unroll
        for (int i = 0; i < 8; ++i) lo |= (uint64_t)(b[i] & 0xff) << (8 * i);
#pragma unroll
        for (int i = 0; i < 8; ++i) hi |= (uint64_t)(b[4 + i] & 0xff) << (8 * i);
        float nrm = norm[g];
        float scale = nrm * (2.0f / 7.0f);
        v8h out[4];
#pragma unroll
        for (int i = 0; i < 32; ++i) {
            int p3 = 3 * i;
            uint32_t qv = (i <= 20) ? (uint32_t)((lo >> p3) & 7)
                                    : (uint32_t)((hi >> (p3 - 32)) & 7);
            float v = fmaf((float)qv, scale, -nrm);
            out[i >> 3][i & 7] = (_Float16)v;
        }
        v8h* dst = (v8h*)(w + (size_t)g * 32);
        dst[0] = out[0]; dst[1] = out[1]; dst[2] = out[2]; dst[3] = out[3];
    } else {
        size_t i = ((size_t)(blk - 2048) * 256 + threadIdx.x) * 8;
        float4 a = *(const float4*)(x + i);
        float4 c = *(const float4*)(x + i + 4);
        v8h r;
        r[0] = (_Float16)a.x; r[1] = (_Float16)a.y; r[2] = (_Float16)a.z; r[3] = (_Float16)a.w;
        r[4] = (_Float16)c.x; r[5] = (_Float16)c.y; r[6] = (_Float16)c.z; r[7] = (_Float16)c.w;
        *(v8h*)(xo + i) = r;
    }
}

// ================== Kernel 2: 256x256 deep-pipelined GEMM ==================
// C[M,N] = A[M,K] * B[N,K]^T + bias.  8 waves (2Mx4N), per-wave 128x64 output.
// LDS: 4-slot FIFO of K-half units (k=32): slot = A[256][32] + B[256][32] = 32 KB.
// Step u: stage unit u+3 (4 gload_lds/thread), vmcnt(12) [3 units in flight],
// barrier, 12 ds_read_b128, 32 MFMA, lgkmcnt(0), barrier. Slot (u+4)&3 == u&3 is
// overwritten only at step u+1, after this step's lgkmcnt(0)+barrier -> race-free.
// XOR swizzle: element (r,k) at line=r>>1, ch=((r&1)*4+(k>>3))^(line&7): every
// 8-lane b128 group hits 8 distinct 16B chunks (conflict-free). gload_lds dest is
// LINEAR (lane x 16B); the GLOBAL source is inverse-swizzled (both-sides rule).
#define KU 32
#define NKU (IN_F / KU)   // 128

__global__ void __launch_bounds__(512, 2)
gemm_kernel(const _Float16* __restrict__ A,   // [M_ROWS][IN_F]
            const _Float16* __restrict__ B,   // [OUT_F][IN_F]
            const float* __restrict__ bias,
            float* __restrict__ C) {
    __shared__ __align__(16) char smem[131072];   // 4 x 32 KB slots

    int pid = blockIdx.x;                    // 512 = 32 pm x 16 pn
    int wg  = (pid & 7) * 64 + (pid >> 3);   // bijective XCD swizzle (512 % 8 == 0)
    int pn  = wg >> 5;                       // per XCD: pn in {2c, 2c+1} -> 4 MB B in L2
    int pm  = wg & 31;
    const int m0 = pm * 256, n0 = pn * 256;

    int t = threadIdx.x;
    int lane = t & 63, wid = t >> 6;
    int wm = wid >> 2, wn = wid & 3;
    int lr = lane & 15, qd = lane >> 4;

    // ---- read-side: swizzled chunk is a per-lane CONSTANT (line&7 == (lr>>1)&7) ----
    int chr  = (((lane & 1) << 2) | qd) ^ ((lr >> 1) & 7);
    int aoff = wm * 8192 + (lr >> 1) * 128 + chr * 16;           // within A region (16 KB)
    int boff = 16384 + wn * 4096 + (lr >> 1) * 128 + chr * 16;   // B region after A

    // ---- stage-side: linear LDS slot s -> inverse-swizzled global (r,c) ----
    int line = t >> 3, chl = t & 7;
    int chd  = chl ^ (line & 7);
    int rr0  = 2 * line + (chd >> 2);
    int cc0  = chd & 3;
    // s = t+512 -> line+64; (line+64)&7 == line&7, so same chd: just +128 rows.
    const _Float16* gA0 = A + (size_t)(m0 + rr0) * IN_F + cc0 * 8;
    const _Float16* gA1 = gA0 + (size_t)128 * IN_F;
    const _Float16* gB0 = B + (size_t)(n0 + rr0) * IN_F + cc0 * 8;
    const _Float16* gB1 = gB0 + (size_t)128 * IN_F;
    const int dA = t * 16;           // linear LDS byte offset (wave-uniform base + lane*16)
    const int dB = 16384 + t * 16;

    v4f acc[8][4] = {};

#define STAGE4(SL2)                                                                 \
    do {                                                                            \
        char* db_ = smem + (SL2) * 32768;                                           \
        __builtin_amdgcn_global_load_lds(                                           \
            (const __attribute__((address_space(1))) void*)gA0,                     \
            (__attribute__((address_space(3))) void*)(db_ + dA), 16, 0, 0);         \
        __builtin_amdgcn_global_load_lds(                                           \
            (const __attribute__((address_space(1))) void*)gA1,                     \
            (__attribute__((address_space(3))) void*)(db_ + dA + 8192), 16, 0, 0);  \
        __builtin_amdgcn_global_load_lds(                                           \
            (const __attribute__((address_space(1))) void*)gB0,                     \
            (__attribute__((address_space(3))) void*)(db_ + dB), 16, 0, 0);         \
        __builtin_amdgcn_global_load_lds(                                           \
            (const __attribute__((address_space(1))) void*)gB1,                     \
            (__attribute__((address_space(3))) void*)(db_ + dB + 8192), 16, 0, 0);  \
    } while (0)

#define STEP(SL, DO_STAGE, VM)                                                      \
    do {                                                                            \
        if (DO_STAGE) {                                                             \
            STAGE4((((SL) + 3) & 3));                                               \
            gA0 += KU; gA1 += KU; gB0 += KU; gB1 += KU;                             \
        }                                                                           \
        asm volatile("s_waitcnt vmcnt(" #VM ")" ::: "memory");                      \
        __builtin_amdgcn_s_barrier();                                               \
        asm volatile("" ::: "memory");  /* keep ds_reads below the barrier */       \
        {                                                                           \
            const char* slb = smem + (SL) * 32768;                                  \
            v8h a0_[4], a1_[4], bb_[4];                                             \
            _Pragma("unroll") for (int i = 0; i < 4; ++i)                           \
                a0_[i] = *(const v8h*)(slb + aoff + i * 1024);                      \
            _Pragma("unroll") for (int j = 0; j < 4; ++j)                           \
                bb_[j] = *(const v8h*)(slb + boff + j * 1024);                      \
            _Pragma("unroll") for (int i = 0; i < 4; ++i)                           \
                a1_[i] = *(const v8h*)(slb + aoff + (i + 4) * 1024);                \
            __builtin_amdgcn_s_setprio(1);                                          \
            _Pragma("unroll") for (int i = 0; i < 4; ++i)                           \
                _Pragma("unroll") for (int j = 0; j < 4; ++j)                       \
                    acc[i][j] = __builtin_amdgcn_mfma_f32_16x16x32_f16(             \
                        a0_[i], bb_[j], acc[i][j], 0, 0, 0);                        \
            _Pragma("unroll") for (int i = 0; i < 4; ++i)                           \
                _Pragma("unroll") for (int j = 0; j < 4; ++j)                       \
                    acc[i + 4][j] = __builtin_amdgcn_mfma_f32_16x16x32_f16(         \
                        a1_[i], bb_[j], acc[i + 4][j], 0, 0, 0);                    \
            __builtin_amdgcn_s_setprio(0);                                          \
        }                                                                           \
        asm volatile("s_waitcnt lgkmcnt(0)" ::: "memory"); /* reads done pre-bar */ \
        __builtin_amdgcn_s_barrier();                                               \
    } while (0)

    // prologue: stage units 0,1,2 into slots 0,1,2
    STAGE4(0); gA0 += KU; gA1 += KU; gB0 += KU; gB1 += KU;
    STAGE4(1); gA0 += KU; gA1 += KU; gB0 += KU; gB1 += KU;
    STAGE4(2); gA0 += KU; gA1 += KU; gB0 += KU; gB1 += KU;

    // steady state: u = 0..123 (stages units 3..126)
#pragma unroll 1
    for (int b2 = 0; b2 < 31; ++b2) {
        STEP(0, 1, 12);
        STEP(1, 1, 12);
        STEP(2, 1, 12);
        STEP(3, 1, 12);
    }
    // tail: u = 124 (stages unit 127 -> slot 3), then drain
    STEP(0, 1, 12);
    STEP(1, 0, 8);
    STEP(2, 0, 4);
    STEP(3, 0, 0);
#undef STEP
#undef STAGE4

    // epilogue: C/D layout col = lane&15, row = qd*4 + rr
#pragma unroll
    for (int j = 0; j < 4; ++j) {
        int n = n0 + wn * 64 + j * 16 + lr;
        float bf = bias[n];
#pragma unroll
        for (int i = 0; i < 8; ++i) {
            int m = m0 + wm * 128 + i * 16 + qd * 4;
#pragma unroll
            for (int rr = 0; rr < 4; ++rr)
                C[(size_t)(m + rr) * OUT_F + n] = acc[i][j][rr] + bf;
        }
    }
}

extern "C" void kernel_launch(void* const* d_in, const int* in_sizes, int n_in,
                              void* d_out, int out_size, void* d_ws, size_t ws_size,
                              hipStream_t stream) {
    (void)in_sizes; (void)n_in; (void)out_size; (void)ws_size;
    const float* x    = (const float*)d_in[0];
    const int*   wq   = (const int*)d_in[1];     // [524288][12] bytes, widened to int32
    const float* wnrm = (const float*)d_in[2];   // [524288]
    const float* bias = (const float*)d_in[3];   // [4096]
    float* out = (float*)d_out;

    _Float16* w16 = (_Float16*)d_ws;                                     // 32 MB
    _Float16* x16 = (_Float16*)((char*)d_ws + (size_t)OUT_F * IN_F * 2); // 64 MB

    // fused prep: 2048 dequant blocks + 16384 cast blocks
    prep_kernel<<<2048 + 16384, 256, 0, stream>>>(wq, wnrm, w16, x, x16);

    int grid = (M_ROWS / 256) * (OUT_F / 256);   // 512
    gemm_kernel<<<grid, 512, 0, stream>>>(x16, w16, bias, out);
}

// Round 3
// 499.559 us; speedup vs baseline: 1.5022x; 1.0655x over previous
//
#include <hip/hip_runtime.h>
#include <hip/hip_fp16.h>
#include <stdint.h>

#define IN_F   4096
#define OUT_F  4096
#define M_ROWS 8192

typedef _Float16 v8h __attribute__((ext_vector_type(8)));
typedef float    v4f __attribute__((ext_vector_type(4)));

// ================== Kernel 1: fused prep ==================
// blocks 0..2047: dequant 3-bit -> f16 w;  blocks 2048..18431: cast x f32 -> f16.
__global__ void __launch_bounds__(256)
prep_kernel(const int* __restrict__ q, const float* __restrict__ norm,
            _Float16* __restrict__ w, const float* __restrict__ x,
            _Float16* __restrict__ xo) {
    int blk = blockIdx.x;
    if (blk < 2048) {
        int g = blk * 256 + threadIdx.x;   // 524288 groups
        const int4* p = (const int4*)(q + (size_t)g * 12);
        int4 q0 = p[0], q1 = p[1], q2 = p[2];
        uint32_t b[12] = {(uint32_t)q0.x, (uint32_t)q0.y, (uint32_t)q0.z, (uint32_t)q0.w,
                          (uint32_t)q1.x, (uint32_t)q1.y, (uint32_t)q1.z, (uint32_t)q1.w,
                          (uint32_t)q2.x, (uint32_t)q2.y, (uint32_t)q2.z, (uint32_t)q2.w};
        uint64_t lo = 0, hi = 0;
#pragma unroll
        for (int i = 0; i < 8; ++i) lo |= (uint64_t)(b[i] & 0xff) << (8 * i);
#pragma unroll
        for (int i = 0; i < 8; ++i) hi |= (uint64_t)(b[4 + i] & 0xff) << (8 * i);
        float nrm = norm[g];
        float scale = nrm * (2.0f / 7.0f);
        v8h out[4];
#pragma unroll
        for (int i = 0; i < 32; ++i) {
            int p3 = 3 * i;
            uint32_t qv = (i <= 20) ? (uint32_t)((lo >> p3) & 7)
                                    : (uint32_t)((hi >> (p3 - 32)) & 7);
            float v = fmaf((float)qv, scale, -nrm);
            out[i >> 3][i & 7] = (_Float16)v;
        }
        v8h* dst = (v8h*)(w + (size_t)g * 32);
        dst[0] = out[0]; dst[1] = out[1]; dst[2] = out[2]; dst[3] = out[3];
    } else {
        size_t i = ((size_t)(blk - 2048) * 256 + threadIdx.x) * 8;
        float4 a = *(const float4*)(x + i);
        float4 c = *(const float4*)(x + i + 4);
        v8h r;
        r[0] = (_Float16)a.x; r[1] = (_Float16)a.y; r[2] = (_Float16)a.z; r[3] = (_Float16)a.w;
        r[4] = (_Float16)c.x; r[5] = (_Float16)c.y; r[6] = (_Float16)c.z; r[7] = (_Float16)c.w;
        *(v8h*)(xo + i) = r;
    }
}

// ================== Kernel 2: 256x256 deep-pipelined GEMM ==================
// C[M,N] = A[M,K] * B[N,K]^T + bias.  8 waves (2Mx4N), per-wave 128x64 output.
// 4-slot LDS FIFO of K-units (k=32): slot = A[256][32] + B[256][32] = 32 KB.
// ONE barrier per step: body u =
//   [ds_read slot u%4 -> STAGE slot (u+3)%4 -> 32 MFMA -> vmcnt(8) -> barrier].
// Race-freedom: every ds_read is consumed by an MFMA before the wave reaches the
// barrier (in-order lgkm + compiler's counted waits), so all reads of slot S retire
// pre-barrier; the stage that overwrites S is issued only after that barrier.
// vmcnt(8) keeps the 2 newest stage-units in flight and guarantees unit u+1
// complete before body u+1.
// XOR swizzle (0 bank conflicts measured R1): gload_lds dest LINEAR, global source
// inverse-swizzled, read side swizzled (both-sides rule).
// XCD raster: 8pm x 8pn rectangle per XCD -> per-XCD traffic (8+8) panels instead
// of (32+2): predicted FETCH 640 -> ~400 MB.
#define KU 32

__global__ void __launch_bounds__(512, 2)
gemm_kernel(const _Float16* __restrict__ A,   // [M_ROWS][IN_F]
            const _Float16* __restrict__ B,   // [OUT_F][IN_F]
            const float* __restrict__ bias,
            float* __restrict__ C) {
    __shared__ __align__(16) char smem[131072];   // 4 x 32 KB slots

    int pid = blockIdx.x;                 // 512 = 32 pm x 16 pn
    int c  = pid & 7;                     // XCD (round-robin dispatch)
    int s  = pid >> 3;                    // 0..63 within XCD
    int pm = ((c & 3) << 3) | (s & 7);    // 8x8 rectangle per XCD
    int pn = ((c >> 2) << 3) | (s >> 3);  // first 32 resident blocks: 8pm x 4pn
    const int m0 = pm * 256, n0 = pn * 256;

    int t = threadIdx.x;
    int lane = t & 63, wid = t >> 6;
    int wm = wid >> 2, wn = wid & 3;
    int lr = lane & 15, qd = lane >> 4;

    // ---- read-side: swizzled chunk is a per-lane CONSTANT ----
    int chr  = (((lane & 1) << 2) | qd) ^ ((lr >> 1) & 7);
    int aoff = wm * 8192 + (lr >> 1) * 128 + chr * 16;           // A region (16 KB)
    int boff = 16384 + wn * 4096 + (lr >> 1) * 128 + chr * 16;   // B region after A

    // ---- stage-side: linear LDS slot -> inverse-swizzled global (r,c) ----
    int line = t >> 3, chl = t & 7;
    int chd  = chl ^ (line & 7);
    int rr0  = 2 * line + (chd >> 2);
    int cc0  = chd & 3;
    const _Float16* gA0 = A + (size_t)(m0 + rr0) * IN_F + cc0 * 8;
    const _Float16* gA1 = gA0 + (size_t)128 * IN_F;
    const _Float16* gB0 = B + (size_t)(n0 + rr0) * IN_F + cc0 * 8;
    const _Float16* gB1 = gB0 + (size_t)128 * IN_F;
    const int dA = t * 16;
    const int dB = 16384 + t * 16;

    v4f acc[8][4] = {};

#define STAGE4(SL2)                                                                 \
    do {                                                                            \
        char* db_ = smem + (SL2) * 32768;                                           \
        __builtin_amdgcn_global_load_lds(                                           \
            (const __attribute__((address_space(1))) void*)gA0,                     \
            (__attribute__((address_space(3))) void*)(db_ + dA), 16, 0, 0);         \
        __builtin_amdgcn_global_load_lds(                                           \
            (const __attribute__((address_space(1))) void*)gA1,                     \
            (__attribute__((address_space(3))) void*)(db_ + dA + 8192), 16, 0, 0);  \
        __builtin_amdgcn_global_load_lds(                                           \
            (const __attribute__((address_space(1))) void*)gB0,                     \
            (__attribute__((address_space(3))) void*)(db_ + dB), 16, 0, 0);         \
        __builtin_amdgcn_global_load_lds(                                           \
            (const __attribute__((address_space(1))) void*)gB1,                     \
            (__attribute__((address_space(3))) void*)(db_ + dB + 8192), 16, 0, 0);  \
    } while (0)

#define STEP(SL, DO_STAGE, VM)                                                      \
    do {                                                                            \
        asm volatile("" ::: "memory");  /* keep ds_reads below previous barrier */  \
        const char* slb = smem + (SL) * 32768;                                      \
        v8h a0_[4], a1_[4], bb_[4];                                                 \
        _Pragma("unroll") for (int i = 0; i < 4; ++i)                               \
            a0_[i] = *(const v8h*)(slb + aoff + i * 1024);                          \
        _Pragma("unroll") for (int j = 0; j < 4; ++j)                               \
            bb_[j] = *(const v8h*)(slb + boff + j * 1024);                          \
        _Pragma("unroll") for (int i = 0; i < 4; ++i)                               \
            a1_[i] = *(const v8h*)(slb + aoff + (i + 4) * 1024);                    \
        if (DO_STAGE) {                                                             \
            STAGE4((((SL) + 3) & 3));                                               \
            gA0 += KU; gA1 += KU; gB0 += KU; gB1 += KU;                             \
        }                                                                           \
        __builtin_amdgcn_s_setprio(1);                                              \
        _Pragma("unroll") for (int i = 0; i < 4; ++i)                               \
            _Pragma("unroll") for (int j = 0; j < 4; ++j)                           \
                acc[i][j] = __builtin_amdgcn_mfma_f32_16x16x32_f16(                 \
                    a0_[i], bb_[j], acc[i][j], 0, 0, 0);                            \
        _Pragma("unroll") for (int i = 0; i < 4; ++i)                               \
            _Pragma("unroll") for (int j = 0; j < 4; ++j)                           \
                acc[i + 4][j] = __builtin_amdgcn_mfma_f32_16x16x32_f16(             \
                    a1_[i], bb_[j], acc[i + 4][j], 0, 0, 0);                        \
        __builtin_amdgcn_s_setprio(0);                                              \
        asm volatile("s_waitcnt vmcnt(" #VM ")" ::: "memory");                      \
        __builtin_amdgcn_s_barrier();                                               \
    } while (0)

    // prologue: stage units 0,1,2 into slots 0,1,2; ensure unit 0 landed
    STAGE4(0); gA0 += KU; gA1 += KU; gB0 += KU; gB1 += KU;
    STAGE4(1); gA0 += KU; gA1 += KU; gB0 += KU; gB1 += KU;
    STAGE4(2); gA0 += KU; gA1 += KU; gB0 += KU; gB1 += KU;
    asm volatile("s_waitcnt vmcnt(8)" ::: "memory");
    __builtin_amdgcn_s_barrier();

    // bodies 0..123 (each stages unit u+3; last loop stage = unit 126)
#pragma unroll 1
    for (int b4 = 0; b4 < 31; ++b4) {
        STEP(0, 1, 8);
        STEP(1, 1, 8);
        STEP(2, 1, 8);
        STEP(3, 1, 8);
    }
    // body 124 stages unit 127; 125..127 drain
    STEP(0, 1, 8);
    STEP(1, 0, 4);
    STEP(2, 0, 0);
    STEP(3, 0, 0);
#undef STEP
#undef STAGE4

    // epilogue: C/D layout col = lane&15, row = qd*4 + rr
#pragma unroll
    for (int j = 0; j < 4; ++j) {
        int n = n0 + wn * 64 + j * 16 + lr;
        float bf = bias[n];
#pragma unroll
        for (int i = 0; i < 8; ++i) {
            int m = m0 + wm * 128 + i * 16 + qd * 4;
#pragma unroll
            for (int rr = 0; rr < 4; ++rr)
                C[(size_t)(m + rr) * OUT_F + n] = acc[i][j][rr] + bf;
        }
    }
}

extern "C" void kernel_launch(void* const* d_in, const int* in_sizes, int n_in,
                              void* d_out, int out_size, void* d_ws, size_t ws_size,
                              hipStream_t stream) {
    (void)in_sizes; (void)n_in; (void)out_size; (void)ws_size;
    const float* x    = (const float*)d_in[0];
    const int*   wq   = (const int*)d_in[1];     // [524288][12] bytes, widened to int32
    const float* wnrm = (const float*)d_in[2];   // [524288]
    const float* bias = (const float*)d_in[3];   // [4096]
    float* out = (float*)d_out;

    _Float16* w16 = (_Float16*)d_ws;                                     // 32 MB
    _Float16* x16 = (_Float16*)((char*)d_ws + (size_t)OUT_F * IN_F * 2); // 64 MB

    prep_kernel<<<2048 + 16384, 256, 0, stream>>>(wq, wnrm, w16, x, x16);

    int grid = (M_ROWS / 256) * (OUT_F / 256);   // 512
    gemm_kernel<<<grid, 512, 0, stream>>>(x16, w16, bias, out);
}

// Round 4
// 499.083 us; speedup vs baseline: 1.5037x; 1.0010x over previous
//
#include <hip/hip_runtime.h>
#include <hip/hip_fp16.h>
#include <stdint.h>

#define IN_F   4096
#define OUT_F  4096
#define M_ROWS 8192

typedef _Float16 v8h __attribute__((ext_vector_type(8)));
typedef float    v4f __attribute__((ext_vector_type(4)));

// ---------------- Kernel 1: dequant 3-bit groups -> f16 weight ----------------
__global__ void __launch_bounds__(256)
dequant_kernel(const int* __restrict__ q, const float* __restrict__ norm,
               _Float16* __restrict__ w) {
    int g = blockIdx.x * blockDim.x + threadIdx.x;   // 524288 groups
    const int4* p = (const int4*)(q + (size_t)g * 12);
    int4 q0 = p[0], q1 = p[1], q2 = p[2];
    uint32_t b[12] = {(uint32_t)q0.x, (uint32_t)q0.y, (uint32_t)q0.z, (uint32_t)q0.w,
                      (uint32_t)q1.x, (uint32_t)q1.y, (uint32_t)q1.z, (uint32_t)q1.w,
                      (uint32_t)q2.x, (uint32_t)q2.y, (uint32_t)q2.z, (uint32_t)q2.w};
    uint64_t lo = 0, hi = 0;
#pragma unroll
    for (int i = 0; i < 8; ++i) lo |= (uint64_t)(b[i] & 0xff) << (8 * i);
#pragma unroll
    for (int i = 0; i < 8; ++i) hi |= (uint64_t)(b[4 + i] & 0xff) << (8 * i);
    float nrm = norm[g];
    float scale = nrm * (2.0f / 7.0f);
    v8h out[4];
#pragma unroll
    for (int i = 0; i < 32; ++i) {
        int p3 = 3 * i;
        uint32_t qv = (i <= 20) ? (uint32_t)((lo >> p3) & 7)
                                : (uint32_t)((hi >> (p3 - 32)) & 7);
        float v = fmaf((float)qv, scale, -nrm);
        out[i >> 3][i & 7] = (_Float16)v;
    }
    v8h* dst = (v8h*)(w + (size_t)g * 32);
    dst[0] = out[0]; dst[1] = out[1]; dst[2] = out[2]; dst[3] = out[3];
}

// ---------------- Kernel 2: cast x f32 -> f16 ----------------
__global__ void __launch_bounds__(256)
castx_kernel(const float* __restrict__ x, _Float16* __restrict__ o) {
    size_t i = ((size_t)blockIdx.x * blockDim.x + threadIdx.x) * 8;
    float4 a = *(const float4*)(x + i);
    float4 b = *(const float4*)(x + i + 4);
    v8h r;
    r[0] = (_Float16)a.x; r[1] = (_Float16)a.y; r[2] = (_Float16)a.z; r[3] = (_Float16)a.w;
    r[4] = (_Float16)b.x; r[5] = (_Float16)b.y; r[6] = (_Float16)b.z; r[7] = (_Float16)b.w;
    *(v8h*)(o + i) = r;
}

// ================== Kernel 3: 256x256 GEMM, reg-double-buffered fragments ======
// R3 post-mortem: ds_read phase (1150 cyc/step/CU) and MFMA phase (1242 cyc) were
// fully SERIALIZED (1150+1242 = 2372 measured). Fix: body u prefetches slot u+1's
// fragments into the alternate register set (no dependency), MFMAs run on the set
// loaded in body u-1 -> LDS pipe drains under the MFMA cluster.
// vmcnt(4) at each barrier retires stage unit u+2 -> slot u+1 resident when body u
// prefetches it. Stage u+3 issued ~1.5 steps before first use (> HBM latency).
// lgkm waits: compiler-managed (cross-body register dependency) -- no inline lgkm.
// Race-freedom: wave's reads of slot u+1 (body u) retire before its MFMAs (body
// u+1), which precede the barrier before stage u+5 (body u+2) overwrites slot u+1.
// Unroll x4 bodies so slot index and register-buffer parity are compile-time.
#define KU 32

__global__ void __launch_bounds__(512, 2)
gemm_kernel(const _Float16* __restrict__ A,   // [M_ROWS][IN_F]
            const _Float16* __restrict__ B,   // [OUT_F][IN_F]
            const float* __restrict__ bias,
            float* __restrict__ C) {
    __shared__ __align__(16) char smem[131072];   // 4 x 32 KB slots

    int pid = blockIdx.x;                 // 512 = 32 pm x 16 pn
    int c  = pid & 7;                     // XCD (round-robin dispatch)
    int s  = pid >> 3;                    // 0..63 within XCD
    int pm = ((c & 3) << 3) | (s & 7);    // 8x8 rectangle per XCD (FETCH 197 MB, R3)
    int pn = ((c >> 2) << 3) | (s >> 3);
    const int m0 = pm * 256, n0 = pn * 256;

    int t = threadIdx.x;
    int lane = t & 63, wid = t >> 6;
    int wm = wid >> 2, wn = wid & 3;
    int lr = lane & 15, qd = lane >> 4;

    // read-side swizzle: chunk is a per-lane constant (0 conflicts measured)
    int chr  = (((lane & 1) << 2) | qd) ^ ((lr >> 1) & 7);
    int aoff = wm * 8192 + (lr >> 1) * 128 + chr * 16;
    int boff = 16384 + wn * 4096 + (lr >> 1) * 128 + chr * 16;

    // stage-side: linear LDS dest, inverse-swizzled global source
    int line = t >> 3, chl = t & 7;
    int chd  = chl ^ (line & 7);
    int rr0  = 2 * line + (chd >> 2);
    int cc0  = chd & 3;
    const _Float16* gA0 = A + (size_t)(m0 + rr0) * IN_F + cc0 * 8;
    const _Float16* gA1 = gA0 + (size_t)128 * IN_F;
    const _Float16* gB0 = B + (size_t)(n0 + rr0) * IN_F + cc0 * 8;
    const _Float16* gB1 = gB0 + (size_t)128 * IN_F;
    const int dA = t * 16;
    const int dB = 16384 + t * 16;

    v4f acc[8][4] = {};
    v8h fa0[8], fb0[4], fa1[8], fb1[4];   // double-buffered fragment sets

#define STAGE4(SL2)                                                                 \
    do {                                                                            \
        char* db_ = smem + (SL2) * 32768;                                           \
        __builtin_amdgcn_global_load_lds(                                           \
            (const __attribute__((address_space(1))) void*)gA0,                     \
            (__attribute__((address_space(3))) void*)(db_ + dA), 16, 0, 0);         \
        __builtin_amdgcn_global_load_lds(                                           \
            (const __attribute__((address_space(1))) void*)gA1,                     \
            (__attribute__((address_space(3))) void*)(db_ + dA + 8192), 16, 0, 0);  \
        __builtin_amdgcn_global_load_lds(                                           \
            (const __attribute__((address_space(1))) void*)gB0,                     \
            (__attribute__((address_space(3))) void*)(db_ + dB), 16, 0, 0);         \
        __builtin_amdgcn_global_load_lds(                                           \
            (const __attribute__((address_space(1))) void*)gB1,                     \
            (__attribute__((address_space(3))) void*)(db_ + dB + 8192), 16, 0, 0);  \
    } while (0)

#define READFRAG(SLOT, FA, FB)                                                      \
    do {                                                                            \
        const char* sp_ = smem + (SLOT) * 32768;                                    \
        _Pragma("unroll") for (int i = 0; i < 8; ++i)                               \
            FA[i] = *(const v8h*)(sp_ + aoff + i * 1024);                           \
        _Pragma("unroll") for (int j = 0; j < 4; ++j)                               \
            FB[j] = *(const v8h*)(sp_ + boff + j * 1024);                           \
    } while (0)

// body: prefetch slot (SL+1)&3 into FNA/FNB, stage unit SL+3, MFMA on FCA/FCB.
#define STEP(SL, FCA, FCB, FNA, FNB, DO_STAGE, DO_PREF, VM)                         \
    do {                                                                            \
        asm volatile("" ::: "memory");  /* keep ds ops below previous barrier */    \
        if (DO_PREF) READFRAG(((SL) + 1) & 3, FNA, FNB);                            \
        if (DO_STAGE) {                                                             \
            STAGE4(((SL) + 3) & 3);                                                 \
            gA0 += KU; gA1 += KU; gB0 += KU; gB1 += KU;                             \
        }                                                                           \
        __builtin_amdgcn_s_setprio(1);                                              \
        _Pragma("unroll") for (int i = 0; i < 8; ++i)                               \
            _Pragma("unroll") for (int j = 0; j < 4; ++j)                           \
                acc[i][j] = __builtin_amdgcn_mfma_f32_16x16x32_f16(                 \
                    FCA[i], FCB[j], acc[i][j], 0, 0, 0);                            \
        __builtin_amdgcn_s_setprio(0);                                              \
        asm volatile("s_waitcnt vmcnt(" #VM ")" ::: "memory");                      \
        __builtin_amdgcn_s_barrier();                                               \
    } while (0)

    // prologue: stage units 0,1,2; ensure units 0 AND 1 landed; read slot 0.
    STAGE4(0); gA0 += KU; gA1 += KU; gB0 += KU; gB1 += KU;
    STAGE4(1); gA0 += KU; gA1 += KU; gB0 += KU; gB1 += KU;
    STAGE4(2); gA0 += KU; gA1 += KU; gB0 += KU; gB1 += KU;
    asm volatile("s_waitcnt vmcnt(4)" ::: "memory");
    __builtin_amdgcn_s_barrier();
    asm volatile("" ::: "memory");
    READFRAG(0, fa0, fb0);

    // bodies 0..123 (each stages unit u+3 <= 126, prefetches slot u+1)
#pragma unroll 1
    for (int b4 = 0; b4 < 31; ++b4) {
        STEP(0, fa0, fb0, fa1, fb1, 1, 1, 4);
        STEP(1, fa1, fb1, fa0, fb0, 1, 1, 4);
        STEP(2, fa0, fb0, fa1, fb1, 1, 1, 4);
        STEP(3, fa1, fb1, fa0, fb0, 1, 1, 4);
    }
    // peeled: body 124 stages unit 127; 125..127 drain (prefetch 125,126,127)
    STEP(0, fa0, fb0, fa1, fb1, 1, 1, 4);
    STEP(1, fa1, fb1, fa0, fb0, 0, 1, 0);
    STEP(2, fa0, fb0, fa1, fb1, 0, 1, 0);
    STEP(3, fa1, fb1, fa0, fb0, 0, 0, 0);
#undef STEP
#undef READFRAG
#undef STAGE4

    // epilogue: C/D layout col = lane&15, row = qd*4 + rr
#pragma unroll
    for (int j = 0; j < 4; ++j) {
        int n = n0 + wn * 64 + j * 16 + lr;
        float bf = bias[n];
#pragma unroll
        for (int i = 0; i < 8; ++i) {
            int m = m0 + wm * 128 + i * 16 + qd * 4;
#pragma unroll
            for (int rr = 0; rr < 4; ++rr)
                C[(size_t)(m + rr) * OUT_F + n] = acc[i][j][rr] + bf;
        }
    }
}

extern "C" void kernel_launch(void* const* d_in, const int* in_sizes, int n_in,
                              void* d_out, int out_size, void* d_ws, size_t ws_size,
                              hipStream_t stream) {
    (void)in_sizes; (void)n_in; (void)out_size; (void)ws_size;
    const float* x    = (const float*)d_in[0];
    const int*   wq   = (const int*)d_in[1];     // [524288][12] bytes, widened to int32
    const float* wnrm = (const float*)d_in[2];   // [524288]
    const float* bias = (const float*)d_in[3];   // [4096]
    float* out = (float*)d_out;

    _Float16* w16 = (_Float16*)d_ws;                                     // 32 MB
    _Float16* x16 = (_Float16*)((char*)d_ws + (size_t)OUT_F * IN_F * 2); // 64 MB

    const int NUM_GROUPS = OUT_F * IN_F / 32;  // 524288
    dequant_kernel<<<NUM_GROUPS / 256, 256, 0, stream>>>(wq, wnrm, w16);
    castx_kernel<<<(size_t)M_ROWS * IN_F / 8 / 256, 256, 0, stream>>>(x, x16);

    int grid = (M_ROWS / 256) * (OUT_F / 256);   // 512
    gemm_kernel<<<grid, 512, 0, stream>>>(x16, w16, bias, out);
}

// Round 5
// 496.238 us; speedup vs baseline: 1.5123x; 1.0057x over previous
//
#include <hip/hip_runtime.h>
#include <hip/hip_fp16.h>
#include <stdint.h>

#define IN_F   4096
#define OUT_F  4096
#define M_ROWS 8192

typedef _Float16 v8h __attribute__((ext_vector_type(8)));
typedef float    v4f __attribute__((ext_vector_type(4)));

// ---------------- Kernel 1: dequant 3-bit groups -> f16 weight ----------------
__global__ void __launch_bounds__(256)
dequant_kernel(const int* __restrict__ q, const float* __restrict__ norm,
               _Float16* __restrict__ w) {
    int g = blockIdx.x * blockDim.x + threadIdx.x;   // 524288 groups
    const int4* p = (const int4*)(q + (size_t)g * 12);
    int4 q0 = p[0], q1 = p[1], q2 = p[2];
    uint32_t b[12] = {(uint32_t)q0.x, (uint32_t)q0.y, (uint32_t)q0.z, (uint32_t)q0.w,
                      (uint32_t)q1.x, (uint32_t)q1.y, (uint32_t)q1.z, (uint32_t)q1.w,
                      (uint32_t)q2.x, (uint32_t)q2.y, (uint32_t)q2.z, (uint32_t)q2.w};
    uint64_t lo = 0, hi = 0;
#pragma unroll
    for (int i = 0; i < 8; ++i) lo |= (uint64_t)(b[i] & 0xff) << (8 * i);
#pragma unroll
    for (int i = 0; i < 8; ++i) hi |= (uint64_t)(b[4 + i] & 0xff) << (8 * i);
    float nrm = norm[g];
    float scale = nrm * (2.0f / 7.0f);
    v8h out[4];
#pragma unroll
    for (int i = 0; i < 32; ++i) {
        int p3 = 3 * i;
        uint32_t qv = (i <= 20) ? (uint32_t)((lo >> p3) & 7)
                                : (uint32_t)((hi >> (p3 - 32)) & 7);
        float v = fmaf((float)qv, scale, -nrm);
        out[i >> 3][i & 7] = (_Float16)v;
    }
    v8h* dst = (v8h*)(w + (size_t)g * 32);
    dst[0] = out[0]; dst[1] = out[1]; dst[2] = out[2]; dst[3] = out[3];
}

// ---------------- Kernel 2: cast x f32 -> f16 ----------------
__global__ void __launch_bounds__(256)
castx_kernel(const float* __restrict__ x, _Float16* __restrict__ o) {
    size_t i = ((size_t)blockIdx.x * blockDim.x + threadIdx.x) * 8;
    float4 a = *(const float4*)(x + i);
    float4 b = *(const float4*)(x + i + 4);
    v8h r;
    r[0] = (_Float16)a.x; r[1] = (_Float16)a.y; r[2] = (_Float16)a.z; r[3] = (_Float16)a.w;
    r[4] = (_Float16)b.x; r[5] = (_Float16)b.y; r[6] = (_Float16)b.z; r[7] = (_Float16)b.w;
    *(v8h*)(o + i) = r;
}

// ====== Kernel 3: 256x256 GEMM, rolling 4-phase interleave (HK-style T3) ======
// R4 post-mortem: full fragment double-buffer needs +96 live VGPRs but acc=128 AGPR
// caps arch VGPRs at 128 (2 waves/SIMD x 256 unified) -> compiler sank the reads,
// schedule reverted. This version needs only ~48 live fragment regs (same as R3):
// the 32-MFMA cluster splits into 4 groups of 8 (a-pair x b[0..3]); reads for later
// groups -- including slot u+1's b (phases B,C) and a01 (phase D) -- issue under the
// current group's MFMAs. Slot u+1 is resident at body-u start (end-of-u-1 vmcnt(4)
// retired stage unit u+1). Reads of slot u+1 are consumed by body u+1's MFMAs
// before the end-of-u+1 barrier, which precedes the overwriting stage (unit u+5,
// body u+2) -> race-free. One barrier/body, counted vmcnt only, no lgkm drains.
#define KU 32

__global__ void __launch_bounds__(512, 2)
gemm_kernel(const _Float16* __restrict__ A,   // [M_ROWS][IN_F]
            const _Float16* __restrict__ B,   // [OUT_F][IN_F]
            const float* __restrict__ bias,
            float* __restrict__ C) {
    __shared__ __align__(16) char smem[131072];   // 4 x 32 KB slots

    int pid = blockIdx.x;                 // 512 = 32 pm x 16 pn
    int c  = pid & 7;                     // XCD (round-robin dispatch)
    int s  = pid >> 3;                    // 0..63 within XCD
    int pm = ((c & 3) << 3) | (s & 7);    // 8x8 rectangle per XCD (FETCH 197 MB)
    int pn = ((c >> 2) << 3) | (s >> 3);
    const int m0 = pm * 256, n0 = pn * 256;

    int t = threadIdx.x;
    int lane = t & 63, wid = t >> 6;
    int wm = wid >> 2, wn = wid & 3;
    int lr = lane & 15, qd = lane >> 4;

    // read-side swizzle: chunk is a per-lane constant (0 conflicts measured)
    int chr  = (((lane & 1) << 2) | qd) ^ ((lr >> 1) & 7);
    int aoff = wm * 8192 + (lr >> 1) * 128 + chr * 16;
    int boff = 16384 + wn * 4096 + (lr >> 1) * 128 + chr * 16;

    // stage-side: linear LDS dest, inverse-swizzled global source
    int line = t >> 3, chl = t & 7;
    int chd  = chl ^ (line & 7);
    int rr0  = 2 * line + (chd >> 2);
    int cc0  = chd & 3;
    const _Float16* gA0 = A + (size_t)(m0 + rr0) * IN_F + cc0 * 8;
    const _Float16* gA1 = gA0 + (size_t)128 * IN_F;
    const _Float16* gB0 = B + (size_t)(n0 + rr0) * IN_F + cc0 * 8;
    const _Float16* gB1 = gB0 + (size_t)128 * IN_F;
    const int dA = t * 16;
    const int dB = 16384 + t * 16;

    v4f acc[8][4] = {};
    v8h p0[2], p1[2], b0s[4], b1s[4];   // rolling fragment regs (~48 live peak)

#define RD(SLOT, OFF) (*(const v8h*)(smem + (SLOT) * 32768 + (OFF)))

#define STAGE4(SL2)                                                                 \
    do {                                                                            \
        char* db_ = smem + (SL2) * 32768;                                           \
        __builtin_amdgcn_global_load_lds(                                           \
            (const __attribute__((address_space(1))) void*)gA0,                     \
            (__attribute__((address_space(3))) void*)(db_ + dA), 16, 0, 0);         \
        __builtin_amdgcn_global_load_lds(                                           \
            (const __attribute__((address_space(1))) void*)gA1,                     \
            (__attribute__((address_space(3))) void*)(db_ + dA + 8192), 16, 0, 0);  \
        __builtin_amdgcn_global_load_lds(                                           \
            (const __attribute__((address_space(1))) void*)gB0,                     \
            (__attribute__((address_space(3))) void*)(db_ + dB), 16, 0, 0);         \
        __builtin_amdgcn_global_load_lds(                                           \
            (const __attribute__((address_space(1))) void*)gB1,                     \
            (__attribute__((address_space(3))) void*)(db_ + dB + 8192), 16, 0, 0);  \
    } while (0)

// MFMA group G (rows 2G,2G+1 of acc) on a-pair PA and b-set BB
#define MFG(G, PA, BB)                                                              \
    do {                                                                            \
        __builtin_amdgcn_s_setprio(1);                                              \
        _Pragma("unroll") for (int j = 0; j < 4; ++j) {                             \
            acc[2 * (G)][j] = __builtin_amdgcn_mfma_f32_16x16x32_f16(               \
                PA[0], BB[j], acc[2 * (G)][j], 0, 0, 0);                            \
            acc[2 * (G) + 1][j] = __builtin_amdgcn_mfma_f32_16x16x32_f16(           \
                PA[1], BB[j], acc[2 * (G) + 1][j], 0, 0, 0);                        \
        }                                                                           \
        __builtin_amdgcn_s_setprio(0);                                              \
    } while (0)

// body: entry invariant: BC = b[0..3] of slot SL, p0 = a[0..1] of slot SL.
// exit: BN = b of slot SL+1, p0 = a01 of slot SL+1 (when DO_NEXT).
#define STEP(SL, BC, BN, DO_STAGE, DO_NEXT, VM)                                     \
    do {                                                                            \
        asm volatile("" ::: "memory");  /* keep ds ops below previous barrier */    \
        /* phase A: read a23 under g0 */                                            \
        p1[0] = RD(SL, aoff + 2 * 1024);                                            \
        p1[1] = RD(SL, aoff + 3 * 1024);                                            \
        MFG(0, p0, BC);                                                             \
        /* phase B: read a45 + next b01, stage, under g1 */                         \
        p0[0] = RD(SL, aoff + 4 * 1024);                                            \
        p0[1] = RD(SL, aoff + 5 * 1024);                                            \
        if (DO_NEXT) {                                                              \
            BN[0] = RD(((SL) + 1) & 3, boff);                                       \
            BN[1] = RD(((SL) + 1) & 3, boff + 1024);                                \
        }                                                                           \
        if (DO_STAGE) {                                                             \
            STAGE4(((SL) + 3) & 3);                                                 \
            gA0 += KU; gA1 += KU; gB0 += KU; gB1 += KU;                             \
        }                                                                           \
        MFG(1, p1, BC);                                                             \
        /* phase C: read a67 + next b23 under g2 */                                 \
        p1[0] = RD(SL, aoff + 6 * 1024);                                            \
        p1[1] = RD(SL, aoff + 7 * 1024);                                            \
        if (DO_NEXT) {                                                              \
            BN[2] = RD(((SL) + 1) & 3, boff + 2048);                                \
            BN[3] = RD(((SL) + 1) & 3, boff + 3072);                                \
        }                                                                           \
        MFG(2, p0, BC);                                                             \
        /* phase D: read next a01 under g3 */                                       \
        if (DO_NEXT) {                                                              \
            p0[0] = RD(((SL) + 1) & 3, aoff);                                       \
            p0[1] = RD(((SL) + 1) & 3, aoff + 1024);                                \
        }                                                                           \
        MFG(3, p1, BC);                                                             \
        asm volatile("s_waitcnt vmcnt(" #VM ")" ::: "memory");                      \
        __builtin_amdgcn_s_barrier();                                               \
    } while (0)

    // prologue: stage units 0,1,2; retire units 0 AND 1; read slot-0 b + a01.
    STAGE4(0); gA0 += KU; gA1 += KU; gB0 += KU; gB1 += KU;
    STAGE4(1); gA0 += KU; gA1 += KU; gB0 += KU; gB1 += KU;
    STAGE4(2); gA0 += KU; gA1 += KU; gB0 += KU; gB1 += KU;
    asm volatile("s_waitcnt vmcnt(4)" ::: "memory");
    __builtin_amdgcn_s_barrier();
    asm volatile("" ::: "memory");
    b0s[0] = RD(0, boff);        b0s[1] = RD(0, boff + 1024);
    b0s[2] = RD(0, boff + 2048); b0s[3] = RD(0, boff + 3072);
    p0[0]  = RD(0, aoff);        p0[1]  = RD(0, aoff + 1024);

    // bodies 0..123 (each stages unit u+3 <= 126; b-set parity = body parity)
#pragma unroll 1
    for (int b4 = 0; b4 < 31; ++b4) {
        STEP(0, b0s, b1s, 1, 1, 4);
        STEP(1, b1s, b0s, 1, 1, 4);
        STEP(2, b0s, b1s, 1, 1, 4);
        STEP(3, b1s, b0s, 1, 1, 4);
    }
    // body 124 stages unit 127; 125 drains unit 127 (vmcnt 0) so body 126 can
    // read slot 3; body 127: no next.
    STEP(0, b0s, b1s, 1, 1, 4);
    STEP(1, b1s, b0s, 0, 1, 0);
    STEP(2, b0s, b1s, 0, 1, 0);
    STEP(3, b1s, b0s, 0, 0, 0);
#undef STEP
#undef MFG
#undef STAGE4
#undef RD

    // epilogue: C/D layout col = lane&15, row = qd*4 + rr
#pragma unroll
    for (int j = 0; j < 4; ++j) {
        int n = n0 + wn * 64 + j * 16 + lr;
        float bf = bias[n];
#pragma unroll
        for (int i = 0; i < 8; ++i) {
            int m = m0 + wm * 128 + i * 16 + qd * 4;
#pragma unroll
            for (int rr = 0; rr < 4; ++rr)
                C[(size_t)(m + rr) * OUT_F + n] = acc[i][j][rr] + bf;
        }
    }
}

extern "C" void kernel_launch(void* const* d_in, const int* in_sizes, int n_in,
                              void* d_out, int out_size, void* d_ws, size_t ws_size,
                              hipStream_t stream) {
    (void)in_sizes; (void)n_in; (void)out_size; (void)ws_size;
    const float* x    = (const float*)d_in[0];
    const int*   wq   = (const int*)d_in[1];     // [524288][12] bytes, widened to int32
    const float* wnrm = (const float*)d_in[2];   // [524288]
    const float* bias = (const float*)d_in[3];   // [4096]
    float* out = (float*)d_out;

    _Float16* w16 = (_Float16*)d_ws;                                     // 32 MB
    _Float16* x16 = (_Float16*)((char*)d_ws + (size_t)OUT_F * IN_F * 2); // 64 MB

    const int NUM_GROUPS = OUT_F * IN_F / 32;  // 524288
    dequant_kernel<<<NUM_GROUPS / 256, 256, 0, stream>>>(wq, wnrm, w16);
    castx_kernel<<<(size_t)M_ROWS * IN_F / 8 / 256, 256, 0, stream>>>(x, x16);

    int grid = (M_ROWS / 256) * (OUT_F / 256);   // 512
    gemm_kernel<<<grid, 512, 0, stream>>>(x16, w16, bias, out);
}